// Round 9
// baseline (190.582 us; speedup 1.0000x reference)
//
#include <hip/hip_runtime.h>
#include <hip/hip_bf16.h>
#include <math.h>

#define Bn 8
#define Tn 2048
#define Cn 384
#define Hn 64
#define SCALE2 0.07362241f            // 384^-0.5 * log2(e); pre-folded into Wq
#define NBLK 512                      // attn grid: 2 blocks/CU exactly

using bf16x8 = __attribute__((ext_vector_type(8))) short;  // 8 bf16 = 4 VGPRs
using f32x4  = __attribute__((ext_vector_type(4))) float;
using u32x4  = __attribute__((ext_vector_type(4))) unsigned;

#define MFMA(a, b, c) __builtin_amdgcn_mfma_f32_16x16x32_bf16((a), (b), (c), 0, 0, 0)

static __device__ __forceinline__ short f2bf(float f) {  // RNE fp32->bf16
  unsigned u = __float_as_uint(f);
  u += 0x7fffu + ((u >> 16) & 1u);
  return (short)(u >> 16);
}
static __device__ __forceinline__ float fexp2(float x) {  // v_exp_f32 (base-2)
#if __has_builtin(__builtin_amdgcn_exp2f)
  return __builtin_amdgcn_exp2f(x);
#else
  return exp2f(x);
#endif
}
static __device__ __forceinline__ float frcp(float x) {   // v_rcp_f32 (~1ulp)
#if __has_builtin(__builtin_amdgcn_rcpf)
  return __builtin_amdgcn_rcpf(x);
#else
  return 1.0f / x;
#endif
}
static __device__ __forceinline__ unsigned pack2(float lo, float hi) {
  return (unsigned)(unsigned short)f2bf(lo) | ((unsigned)(unsigned short)f2bf(hi) << 16);
}
// Typed (TBAA-safe) LDS 16B gather: 4 x u32 loads, compiler merges to b128.
static __device__ __forceinline__ bf16x8 ldp(const unsigned* p) {
  u32x4 t; t[0] = p[0]; t[1] = p[1]; t[2] = p[2]; t[3] = p[3];
  return __builtin_bit_cast(bf16x8, t);
}
// Software grid barrier (graph-capture-safe; co-residency by construction:
// LDS 64.5KB -> exactly 2 blocks/CU x 256 CU = 512 = grid).
static __device__ __forceinline__ void grid_barrier(unsigned* cnt) {
  __syncthreads();
  if (threadIdx.x == 0) {
    __threadfence();                          // release my Lsum atomics
    atomicAdd(cnt, 1u);                       // device-scope arrive
    while (__hip_atomic_load(cnt, __ATOMIC_ACQUIRE, __HIP_MEMORY_SCOPE_AGENT)
           < (unsigned)NBLK)
      __builtin_amdgcn_s_sleep(8);
  }
  __syncthreads();
}

// ---------------- K0: W -> WbT (192x384) bf16 (Wq pre-scaled) + zero Lsum ---
__global__ __launch_bounds__(256) void wconv_kernel(
    const float* __restrict__ Wq, const float* __restrict__ Wk,
    const float* __restrict__ Wv, short* __restrict__ WbT,
    float* __restrict__ Lsum, unsigned* __restrict__ bar) {
  int idx = blockIdx.x * 256 + threadIdx.x;  // n*384 + k, 73728 total
  if (idx < Bn * Tn) Lsum[idx] = 0.f;        // 16384 floats, pre-attn
  if (idx == 0) *bar = 0u;                   // grid-barrier counter
  int n = idx / 384, k = idx - n * 384;
  const float* W = (n < 64) ? Wq : (n < 128) ? Wk : Wv;
  float wv = W[k * 64 + (n & 63)];
  if (n < 64) wv *= SCALE2;                  // fold score scale into q
  WbT[idx] = f2bf(wv);
}

// ---------------- K1: proj GEMM, 16-row tiles (1024 blocks, 4/CU) -----------
__global__ __launch_bounds__(256) void proj_kernel(
    const float* __restrict__ x, const short* __restrict__ WbT,
    short* __restrict__ qb, short* __restrict__ kb, short* __restrict__ vT) {
  __shared__ short xs[16][392];    // stride 392: banks 2-way (free)
  __shared__ short vtile[64][20];  // v-tile transpose bounce
  const int tid = threadIdx.x;
  const int t0 = blockIdx.x * 16;  // global row (b*2048 + t)
  const float* xb = x + (size_t)t0 * Cn;
  #pragma unroll
  for (int i = 0; i < 6; ++i) {
    int j = tid + i * 256;  // float4 index, 1536 total
    int row = j / 96, colv = (j - row * 96) * 4;
    float4 v = *(const float4*)(xb + row * Cn + colv);
    short4 s4; s4.x = f2bf(v.x); s4.y = f2bf(v.y); s4.z = f2bf(v.z); s4.w = f2bf(v.w);
    *(short4*)(&xs[row][colv]) = s4;
  }
  __syncthreads();
  const int w = tid >> 6, l15 = tid & 15, quad = (tid & 63) >> 4;
  f32x4 acc[3] = {};
  for (int ks = 0; ks < 12; ++ks) {
    bf16x8 a = *(const bf16x8*)(&xs[l15][ks * 32 + quad * 8]);
    #pragma unroll
    for (int cf = 0; cf < 3; ++cf) {
      bf16x8 bfr = *(const bf16x8*)(WbT + (size_t)(48 * w + 16 * cf + l15) * Cn + ks * 32 + quad * 8);
      acc[cf] = MFMA(a, bfr, acc[cf]);
    }
  }
  #pragma unroll
  for (int cf = 0; cf < 3; ++cf) {
    int cbase = 48 * w + 16 * cf, c = cbase + l15;
    #pragma unroll
    for (int r = 0; r < 4; ++r) {
      int row = t0 + quad * 4 + r;
      short val = f2bf(acc[cf][r]);
      if (cbase < 64)       qb[(size_t)row * Hn + c] = val;
      else if (cbase < 128) kb[(size_t)row * Hn + (c - 64)] = val;
      else                  vtile[c - 128][quad * 4 + r] = val;
    }
  }
  __syncthreads();
  const int b = t0 >> 11, t0l = t0 & 2047;
  int h = tid >> 2, tseg = (tid & 3) * 4;
  *(short4*)(vT + ((size_t)(b * Hn + h)) * Tn + t0l + tseg) =
      *(const short4*)(&vtile[h][tseg]);
}

// ---------------- K2: FUSED attn, NO persistent E (recompute in phase 2) ----
// 512 blocks x 512 thr, 2 blocks/CU (LDS 64.5KB), barrier-safe.
// PHASE 1 = r4-colstats verbatim: each block is TWO 256-thread units
// (h = tid>>8). Unit = 2*bid + h -> (b1, colchunk-pair j1, eighth u).
// Fixed s-chunk per run -> column sums accumulate in 4 REGISTERS across all
// t-groups (no butterfly, no per-item atomics). 2-deep A-frag prefetch.
// redl LDS reduce; one 64-wide global atomicAdd flush per run (131K total
// atomics, 8x fewer than r8's flush).
// Grid barrier; rcpL -> lsum_lds.
// PHASE 2 = pvpass with QK RECOMPUTE (no Ereg/eextra -> no state held across
// the barrier): per item: loadV early (mB) || QK MFMA (mA) -> loadK next ->
// exp2*rcpL -> pack -> per-wave XOR-swizzled LDS transpose -> 8 PV MFMA (mB).
// Cross-wave reduce via red[4][32][64]; coalesced float4 stores.
__global__ __launch_bounds__(512)
__attribute__((amdgpu_waves_per_eu(4, 4)))
void attn_kernel(
    const short* __restrict__ qb, const short* __restrict__ kb,
    const short* __restrict__ vT, float* __restrict__ Lsum,
    unsigned* __restrict__ bar, float* __restrict__ out) {
  __shared__ alignas(16) float redl[2][64][17];  // per-half colstats reduce
  __shared__ alignas(16) float lsum_lds[2048];   // rcpL after barrier (8KB)
  __shared__ alignas(16) unsigned plds[8][512];  // per-wave 2KB P tile (16KB)
  __shared__ alignas(16) float red[4][32][64];   // cross-wave reduce (32KB)

  const int bid = blockIdx.x;
  const int tid = threadIdx.x;
  const int l15 = tid & 15, quad = (tid & 63) >> 4;

  // ================= PHASE 1: column exp-sums (colstats structure) ==========
  {
    const int h = tid >> 8;                // sub-unit 0/1 (256 thr each)
    const int stid = tid & 255;
    const int w1 = stid >> 6;
    const int unit = 2 * bid + h;          // 1024 units total
    const int b1 = unit >> 7, rem = unit & 127;
    const int j1 = rem >> 3, u = rem & 7;
    const int lo1 = (u * 33) >> 3, hi1 = ((u + 1) * 33) >> 3;  // 4-5 entries
    const int big = 32 - j1;

    auto run = [&](const int i, const int k0, const int k1) {
      const int s0 = i << 6;
      float l[4] = {0.f, 0.f, 0.f, 0.f};
      const int n = k1 - k0;
      if (n > 0) {                         // half-block-uniform: barrier-safe
        bf16x8 bk[8];
        #pragma unroll
        for (int nf = 0; nf < 4; ++nf) {
          const size_t krow = (size_t)(b1 * Tn + s0 + 16 * nf + l15) * Hn;
          bk[2 * nf]     = *(const bf16x8*)(kb + krow + quad * 8);
          bk[2 * nf + 1] = *(const bf16x8*)(kb + krow + 32 + quad * 8);
        }
        auto cload = [&](bf16x8& A0, bf16x8& A1, int k) {
          size_t ar = (size_t)(b1 * Tn + ((i + k) << 6) + 16 * w1 + l15) * Hn;
          A0 = *(const bf16x8*)(qb + ar + quad * 8);
          A1 = *(const bf16x8*)(qb + ar + 32 + quad * 8);
        };
        auto ccomp = [&](bf16x8 A0, bf16x8 A1, int k) {
          f32x4 sc[4] = {};
          __builtin_amdgcn_s_setprio(1);
          #pragma unroll
          for (int nf = 0; nf < 4; ++nf) {
            sc[nf] = MFMA(A0, bk[2 * nf], sc[nf]);
            sc[nf] = MFMA(A1, bk[2 * nf + 1], sc[nf]);
          }
          __builtin_amdgcn_s_setprio(0);
          const bool diag = (k == 0);
          const int tb = ((i + k) << 6) + 16 * w1 + quad * 4;
          #pragma unroll
          for (int nf = 0; nf < 4; ++nf) {
            int s = s0 + 16 * nf + l15;
            #pragma unroll
            for (int r = 0; r < 4; ++r) {
              float v = sc[nf][r];                     // exp2-domain score
              if (diag && (tb + r) < s) v = -INFINITY; // exp2(-inf) = 0
              l[nf] += fexp2(v);
            }
          }
        };
        bf16x8 a0A, a1A, a0B, a1B;         // 2-deep prefetch (reg-lean)
        cload(a0A, a1A, k0);
        if (n > 1) cload(a0B, a1B, k0 + 1);
        int k = k0;
        while (k + 2 < k1) {
          ccomp(a0A, a1A, k);     cload(a0A, a1A, k + 2);
          ccomp(a0B, a1B, k + 1); if (k + 3 < k1) cload(a0B, a1B, k + 3);
          k += 2;
        }
        if (k < k1)     ccomp(a0A, a1A, k);
        if (k + 1 < k1) ccomp(a0B, a1B, k + 1);
      }
      __syncthreads();  // protect redl reuse across runs (uniform count)
      #pragma unroll
      for (int nf = 0; nf < 4; ++nf) redl[h][16 * nf + l15][w1 * 4 + quad] = l[nf];
      __syncthreads();
      if (stid < 64) {
        float ls = 0.f;
        #pragma unroll
        for (int q2 = 0; q2 < 16; ++q2) ls += redl[h][stid][q2];
        atomicAdd(&Lsum[b1 * Tn + s0 + stid], ls);   // dense column sums
      }
    };
    run(j1, lo1, min(hi1, big));                     // big member: colchunk j1
    run(31 - j1, max(lo1, big) - big, hi1 - big);    // small: colchunk 31-j1
  }

  grid_barrier(bar);

  // ================= PHASE 2: out = (exp(QK^T)/L) . vS^T, recompute ========
  const int b = bid & 7;                   // XCD-locked batch (phase-2 map)
  const int r_ = bid >> 3;                 // 0..63
  const int j = r_ >> 2;                   // pair 0..15
  const int quarter = r_ & 3;
  const int tA = j, tB = 31 - j;           // light tile, heavy tile
  const int w = tid >> 6;
  const int lo = (w * 33) >> 3, hi = ((w + 1) * 33) >> 3;  // 4-5 items/wave
  const int tb0 = (tA << 6) + (quarter << 4);
  const int tb1 = (tB << 6) + (quarter << 4);
  const size_t QKbase = (size_t)b * Tn * Hn;
  const size_t Vbase  = (size_t)b * Hn * Tn;

  for (int s = tid; s < 2048; s += 512)    // agent-scope load: coherent
    lsum_lds[s] = frcp(__hip_atomic_load(&Lsum[b * Tn + s],
                                         __ATOMIC_RELAXED,
                                         __HIP_MEMORY_SCOPE_AGENT));
  __syncthreads();

  // XOR swizzle: byte ^= (l15&7)<<4 breaks the 128B-row same-bank pattern.
  const int swz = (l15 & 7) << 4;
  int wroff[8];                            // u32 offsets: s = 16nf+4q+{2p,2p+1}
  #pragma unroll
  for (int nf = 0; nf < 4; ++nf)
    #pragma unroll
    for (int p = 0; p < 2; ++p)
      wroff[2 * nf + p] = (l15 * 128 + ((nf * 32 + quad * 8 + p * 4) ^ swz)) >> 2;
  const int rd0 = (l15 * 128 + ((quad * 16) ^ swz)) >> 2;        // s = 8q..8q+7
  const int rd1 = (l15 * 128 + ((64 + quad * 16) ^ swz)) >> 2;   // s = 32+8q..+7

  bf16x8 mA[8], mB[8];
  auto loadK = [&](int ch) {               // A[m=s][k=h] frags for S^T -> mA
    const int s0 = ch << 6;
    #pragma unroll
    for (int nf = 0; nf < 4; ++nf) {
      const size_t kr = QKbase + (size_t)(s0 + 16 * nf + l15) * Hn;
      mA[2 * nf]     = *(const bf16x8*)(kb + kr + quad * 8);
      mA[2 * nf + 1] = *(const bf16x8*)(kb + kr + 32 + quad * 8);
    }
  };
  auto loadV = [&](int ch) {               // B[n=h][k=s] frags for PV -> mB
    const int s0 = ch << 6;
    #pragma unroll
    for (int nf = 0; nf < 4; ++nf) {
      const size_t vr = Vbase + (size_t)(16 * nf + l15) * Tn + s0;
      mB[2 * nf]     = *(const bf16x8*)(vT + vr + quad * 8);
      mB[2 * nf + 1] = *(const bf16x8*)(vT + vr + 32 + quad * 8);
    }
  };

  auto pvpass = [&](bool stripB) {
    const int g0 = stripB ? ((lo > tA + 1) ? lo : tA + 1) : lo;
    const int g1 = stripB ? hi : ((hi < tA + 1) ? hi : tA + 1);
    f32x4 acc[4] = {};
    if (g0 < g1) {
      const int tbase = stripB ? tb1 : tb0;
      const int tile  = stripB ? tB : tA;
      const int tg = tbase + l15;
      const size_t qrow = QKbase + (size_t)tg * Hn;
      const bf16x8 qf0 = *(const bf16x8*)(qb + qrow + quad * 8);
      const bf16x8 qf1 = *(const bf16x8*)(qb + qrow + 32 + quad * 8);
      loadK(stripB ? g0 - tA - 1 : g0);
      #pragma unroll
      for (int i = 0; i < 5; ++i) {
        const int g = lo + i;
        if (g >= g0 && g < g1) {
          const int ch = stripB ? g - tA - 1 : g;
          loadV(ch);                       // early issue: consumed by PV below
          f32x4 sc[4] = {};                // D[s][t]: lane&15 = t
          __builtin_amdgcn_s_setprio(1);
          #pragma unroll
          for (int nf = 0; nf < 4; ++nf) {
            sc[nf] = MFMA(mA[2 * nf], qf0, sc[nf]);
            sc[nf] = MFMA(mA[2 * nf + 1], qf1, sc[nf]);
          }
          __builtin_amdgcn_s_setprio(0);
          if (g + 1 < g1) loadK(ch + 1);   // next K under exp/pack/PV
          const bool diag = (ch == tile);
          #pragma unroll
          for (int nf = 0; nf < 4; ++nf) {
            float4 rl4 = *(const float4*)&lsum_lds[(ch << 6) + 16 * nf + 4 * quad];
            float p[4];
            #pragma unroll
            for (int r = 0; r < 4; ++r) {
              float v = sc[nf][r];
              const int s = (ch << 6) + 16 * nf + 4 * quad + r;
              if (diag && tg < s) v = -INFINITY;       // causal: exp2(-inf)=0
              p[r] = fexp2(v) * (&rl4.x)[r];           // P = E/L in [0,1]
            }
            plds[w][wroff[2 * nf]]     = pack2(p[0], p[1]);
            plds[w][wroff[2 * nf + 1]] = pack2(p[2], p[3]);
          }
          const bf16x8 a0 = ldp(&plds[w][rd0]);  // typed u32: order preserved
          const bf16x8 a1 = ldp(&plds[w][rd1]);
          __builtin_amdgcn_s_setprio(1);
          #pragma unroll
          for (int nf = 0; nf < 4; ++nf) {       // D[t][h]: lane&15=h, t=4q+r
            acc[nf] = MFMA(a0, mB[2 * nf], acc[nf]);
            acc[nf] = MFMA(a1, mB[2 * nf + 1], acc[nf]);
          }
          __builtin_amdgcn_s_setprio(0);
        }
      }
    }
    const int rb = stripB ? 16 : 0;
    if (w < 4) {
      #pragma unroll
      for (int nf = 0; nf < 4; ++nf)
        #pragma unroll
        for (int r = 0; r < 4; ++r)
          red[w][rb + quad * 4 + r][16 * nf + l15] = acc[nf][r];
    }
    __syncthreads();
    if (w >= 4) {
      #pragma unroll
      for (int nf = 0; nf < 4; ++nf)
        #pragma unroll
        for (int r = 0; r < 4; ++r)
          red[w - 4][rb + quad * 4 + r][16 * nf + l15] += acc[nf][r];
    }
    __syncthreads();
  };
  pvpass(false);                                // tile j rows -> red[][0:16]
  pvpass(true);                                 // tile 31-j rows -> red[][16:32]

  {
    const int row = tid >> 4, c4 = (tid & 15) * 4;  // 32 rows x 16 col-quads
    float4 s0 = *(const float4*)(&red[0][row][c4]);
    float4 s1 = *(const float4*)(&red[1][row][c4]);
    float4 s2 = *(const float4*)(&red[2][row][c4]);
    float4 s3 = *(const float4*)(&red[3][row][c4]);
    float4 t;
    t.x = (s0.x + s1.x) + (s2.x + s3.x);
    t.y = (s0.y + s1.y) + (s2.y + s3.y);
    t.z = (s0.z + s1.z) + (s2.z + s3.z);
    t.w = (s0.w + s1.w) + (s2.w + s3.w);
    const int trow = (row < 16) ? (tb0 + row) : (tb1 + row - 16);
    *(float4*)(&out[QKbase + (size_t)trow * Hn + c4]) = t;
  }
}

extern "C" void kernel_launch(void* const* d_in, const int* in_sizes, int n_in,
                              void* d_out, int out_size, void* d_ws, size_t ws_size,
                              hipStream_t stream) {
  const float* x  = (const float*)d_in[0];
  const float* Wq = (const float*)d_in[1];
  const float* Wk = (const float*)d_in[2];
  const float* Wv = (const float*)d_in[3];
  char* ws = (char*)d_ws;                          // needs ~6.6 MB
  short* qb   = (short*)(ws);                      // 2 MB (T,H) (q pre-scaled)
  short* kb   = (short*)(ws + 2097152);            // 2 MB (T,H)
  short* vT   = (short*)(ws + 4194304);            // 2 MB (H,T)
  short* WbT  = (short*)(ws + 6291456);            // 144 KB
  float* Lsum = (float*)(ws + 6438912);            // 64 KB dense column sums
  unsigned* bar = (unsigned*)(ws + 6504448);       // grid-barrier counter
  float* outp = (float*)d_out;

  hipLaunchKernelGGL(wconv_kernel, dim3(288), dim3(256), 0, stream, Wq, Wk, Wv, WbT, Lsum, bar);
  hipLaunchKernelGGL(proj_kernel, dim3(Bn * Tn / 16), dim3(256), 0, stream, x, WbT, qb, kb, vT);
  hipLaunchKernelGGL(attn_kernel, dim3(NBLK), dim3(512), 0, stream, qb, kb, vT, Lsum, bar, outp);
}

// Round 12
// 150.995 us; speedup vs baseline: 1.2622x; 1.2622x over previous
//
#include <hip/hip_runtime.h>
#include <hip/hip_bf16.h>
#include <math.h>

#define Bn 8
#define Tn 2048
#define Cn 384
#define Hn 64
#define SCALE2 0.07362241f            // 384^-0.5 * log2(e); pre-folded into Wq

using bf16x8 = __attribute__((ext_vector_type(8))) short;  // 8 bf16 = 4 VGPRs
using f32x4  = __attribute__((ext_vector_type(4))) float;
using u32x4  = __attribute__((ext_vector_type(4))) unsigned;

#define MFMA(a, b, c) __builtin_amdgcn_mfma_f32_16x16x32_bf16((a), (b), (c), 0, 0, 0)

static __device__ __forceinline__ short f2bf(float f) {  // RNE fp32->bf16
  unsigned u = __float_as_uint(f);
  u += 0x7fffu + ((u >> 16) & 1u);
  return (short)(u >> 16);
}
static __device__ __forceinline__ float fexp2(float x) {  // v_exp_f32 (base-2)
#if __has_builtin(__builtin_amdgcn_exp2f)
  return __builtin_amdgcn_exp2f(x);
#else
  return exp2f(x);
#endif
}
static __device__ __forceinline__ float frcp(float x) {   // v_rcp_f32 (~1ulp)
#if __has_builtin(__builtin_amdgcn_rcpf)
  return __builtin_amdgcn_rcpf(x);
#else
  return 1.0f / x;
#endif
}
static __device__ __forceinline__ unsigned pack2(float lo, float hi) {
  return (unsigned)(unsigned short)f2bf(lo) | ((unsigned)(unsigned short)f2bf(hi) << 16);
}
// Typed (TBAA-safe) LDS 16B gather: 4 x u32 loads, compiler merges to b128.
static __device__ __forceinline__ bf16x8 ldp(const unsigned* p) {
  u32x4 t; t[0] = p[0]; t[1] = p[1]; t[2] = p[2]; t[3] = p[3];
  return __builtin_bit_cast(bf16x8, t);
}

// ---------------- K0: W -> WbT (192x384) bf16 (Wq pre-scaled) + zero Lsum ---
__global__ __launch_bounds__(256) void wconv_kernel(
    const float* __restrict__ Wq, const float* __restrict__ Wk,
    const float* __restrict__ Wv, short* __restrict__ WbT,
    float* __restrict__ Lsum) {
  int idx = blockIdx.x * 256 + threadIdx.x;  // n*384 + k, 73728 total
  if (idx < Bn * Tn) Lsum[idx] = 0.f;        // 16384 floats, pre-colstats
  int n = idx / 384, k = idx - n * 384;
  const float* W = (n < 64) ? Wq : (n < 128) ? Wk : Wv;
  float wv = W[k * 64 + (n & 63)];
  if (n < 64) wv *= SCALE2;                  // fold score scale into q
  WbT[idx] = f2bf(wv);
}

// ---------------- K1: proj GEMM, 16-row tiles (1024 blocks, 4/CU) -----------
__global__ __launch_bounds__(256) void proj_kernel(
    const float* __restrict__ x, const short* __restrict__ WbT,
    short* __restrict__ qb, short* __restrict__ kb, short* __restrict__ vT) {
  __shared__ short xs[16][392];    // stride 392: banks 2-way (free)
  __shared__ short vtile[64][20];  // v-tile transpose bounce
  const int tid = threadIdx.x;
  const int t0 = blockIdx.x * 16;  // global row (b*2048 + t)
  const float* xb = x + (size_t)t0 * Cn;
  #pragma unroll
  for (int i = 0; i < 6; ++i) {
    int j = tid + i * 256;  // float4 index, 1536 total
    int row = j / 96, colv = (j - row * 96) * 4;
    float4 v = *(const float4*)(xb + row * Cn + colv);
    short4 s4; s4.x = f2bf(v.x); s4.y = f2bf(v.y); s4.z = f2bf(v.z); s4.w = f2bf(v.w);
    *(short4*)(&xs[row][colv]) = s4;
  }
  __syncthreads();
  const int w = tid >> 6, l15 = tid & 15, quad = (tid & 63) >> 4;
  f32x4 acc[3] = {};
  for (int ks = 0; ks < 12; ++ks) {
    bf16x8 a = *(const bf16x8*)(&xs[l15][ks * 32 + quad * 8]);
    #pragma unroll
    for (int cf = 0; cf < 3; ++cf) {
      bf16x8 bfr = *(const bf16x8*)(WbT + (size_t)(48 * w + 16 * cf + l15) * Cn + ks * 32 + quad * 8);
      acc[cf] = MFMA(a, bfr, acc[cf]);
    }
  }
  #pragma unroll
  for (int cf = 0; cf < 3; ++cf) {
    int cbase = 48 * w + 16 * cf, c = cbase + l15;
    #pragma unroll
    for (int r = 0; r < 4; ++r) {
      int row = t0 + quad * 4 + r;
      short val = f2bf(acc[cf][r]);
      if (cbase < 64)       qb[(size_t)row * Hn + c] = val;
      else if (cbase < 128) kb[(size_t)row * Hn + (c - 64)] = val;
      else                  vtile[c - 128][quad * 4 + r] = val;
    }
  }
  __syncthreads();
  const int b = t0 >> 11, t0l = t0 & 2047;
  int h = tid >> 2, tseg = (tid & 3) * 4;
  *(short4*)(vT + ((size_t)(b * Hn + h)) * Tn + t0l + tseg) =
      *(const short4*)(&vtile[h][tseg]);
}

// ---------------- K2: column exp-sums -> atomicAdd Lsum (high-TLP) ----------
// 2048 blocks x 256 thr (launch_bounds(256,4): cap 128, need ~80; 4 blocks/CU
// = 16 waves/CU vs r4's 8 -> TLP hides the L2 chunk-load latency chain).
// Pair (colchunk j: 32-j t-groups) + (colchunk 31-j: j+1) = 33 items;
// unit = (b = bid&7, j, u sixteenth): 2-3 items each. Fixed s-chunk per run
// -> column sums accumulate in 4 registers (no cross-lane, no LDS atomics).
// q pre-scaled: sc is already the exp2 exponent.
__global__ __launch_bounds__(256, 4) void colstats_kernel(
    const short* __restrict__ qb, const short* __restrict__ kb,
    float* __restrict__ Lsum) {
  const int bid = blockIdx.x;
  const int b = bid & 7;                   // XCD-locked batch
  const int rem = bid >> 3;                // 0..255
  const int j = rem >> 4, u = rem & 15;
  const int lo = (u * 33) >> 4, hi = ((u + 1) * 33) >> 4;  // 2-3 items
  const int big = 32 - j;
  const int tid = threadIdx.x, w = tid >> 6, l15 = tid & 15, quad = (tid & 63) >> 4;
  __shared__ float redl[64][17];

  auto run = [&](const int i, const int k0, const int k1) {
    const int s0 = i << 6;
    float l[4] = {0.f, 0.f, 0.f, 0.f};
    const int n = k1 - k0;
    if (n > 0) {                           // block-uniform: barrier-safe
      bf16x8 bk[8];
      #pragma unroll
      for (int nf = 0; nf < 4; ++nf) {
        const size_t krow = (size_t)(b * Tn + s0 + 16 * nf + l15) * Hn;
        bk[2 * nf]     = *(const bf16x8*)(kb + krow + quad * 8);
        bk[2 * nf + 1] = *(const bf16x8*)(kb + krow + 32 + quad * 8);
      }
      auto cload = [&](bf16x8& A0, bf16x8& A1, int k) {
        size_t ar = (size_t)(b * Tn + ((i + k) << 6) + 16 * w + l15) * Hn;
        A0 = *(const bf16x8*)(qb + ar + quad * 8);
        A1 = *(const bf16x8*)(qb + ar + 32 + quad * 8);
      };
      auto ccomp = [&](bf16x8 A0, bf16x8 A1, int k) {
        f32x4 sc[4] = {};
        __builtin_amdgcn_s_setprio(1);
        #pragma unroll
        for (int nf = 0; nf < 4; ++nf) {
          sc[nf] = MFMA(A0, bk[2 * nf], sc[nf]);
          sc[nf] = MFMA(A1, bk[2 * nf + 1], sc[nf]);
        }
        __builtin_amdgcn_s_setprio(0);
        const bool diag = (k == 0);
        const int tb = ((i + k) << 6) + 16 * w + quad * 4;
        #pragma unroll
        for (int nf = 0; nf < 4; ++nf) {
          int s = s0 + 16 * nf + l15;
          #pragma unroll
          for (int r = 0; r < 4; ++r) {
            float v = sc[nf][r];                     // exp2-domain score
            if (diag && (tb + r) < s) v = -INFINITY; // exp2(-inf) = 0
            l[nf] += fexp2(v);
          }
        }
      };
      bf16x8 a0A, a1A, a0B, a1B;           // 2-deep prefetch (reg-lean)
      cload(a0A, a1A, k0);
      if (n > 1) cload(a0B, a1B, k0 + 1);
      int k = k0;
      while (k + 2 < k1) {
        ccomp(a0A, a1A, k);     cload(a0A, a1A, k + 2);
        ccomp(a0B, a1B, k + 1); if (k + 3 < k1) cload(a0B, a1B, k + 3);
        k += 2;
      }
      if (k < k1)     ccomp(a0A, a1A, k);
      if (k + 1 < k1) ccomp(a0B, a1B, k + 1);
    }
    __syncthreads();  // protect redl reuse across runs (uniform count)
    #pragma unroll
    for (int nf = 0; nf < 4; ++nf) redl[16 * nf + l15][w * 4 + quad] = l[nf];
    __syncthreads();
    if (tid < 64) {
      float ls = 0.f;
      #pragma unroll
      for (int q2 = 0; q2 < 16; ++q2) ls += redl[tid][q2];
      atomicAdd(&Lsum[b * Tn + s0 + tid], ls);  // dense column sums
    }
  };
  run(j, lo, min(hi, big));                       // big member: colchunk j
  run(31 - j, max(lo, big) - big, hi - big);      // small: colchunk 31-j
}

// ---------------- K3: out = (exp(QK^T)/L)_tri . vT^T, 16-row strips ---------
// 1024 blocks x 256 thr (launch_bounds(256,4): cap 128, need ~115, 4/CU =
// 16 waves/CU -> 2x r4's TLP). Block = (tile = 31-(bid>>5) heavy-first,
// b = bid&7 XCD-locked, quarter): 16 output rows; waves split chunks stride 4.
// Per chunk: loadV(ch) issued FIRST (latency under QK) -> 8 QK MFMA (kf) ->
// loadK(ch+4) (kf dead) -> exp2*rcpL + pack -> per-wave XOR-swizzled LDS
// transpose (typed u32, no barriers) -> 8 PV MFMA -> loadV(ch+4).
// Cross-wave reduce via red[4][16][64]; one coalesced float4 store/elem.
__global__ __launch_bounds__(256, 4) void outg_kernel(
    const short* __restrict__ qb, const short* __restrict__ kb,
    const short* __restrict__ vT, const float* __restrict__ Lsum,
    float* __restrict__ out) {
  const int bid = blockIdx.x;
  const int tile = 31 - (bid >> 5);        // heavy (many-chunk) tiles first
  const int sub = bid & 31;
  const int b = sub & 7, quarter = sub >> 3;
  const int nch = tile + 1;
  const int tid = threadIdx.x, w = tid >> 6, l15 = tid & 15, quad = (tid & 63) >> 4;
  __shared__ alignas(16) unsigned plds[4][512];  // per-wave 2KB P tile (8KB)
  __shared__ alignas(16) float red[4][16][64];   // cross-wave reduce (16KB)
  __shared__ alignas(16) float rcpl[2048];       // 1/L[s] (8KB)

  const int smax = nch << 6;
  for (int s = tid; s < smax; s += 256)    // coalesced; v_rcp (~1ulp)
    rcpl[s] = frcp(Lsum[b * Tn + s]);
  __syncthreads();

  // XOR swizzle: byte ^= (l15&7)<<4 breaks the 128B-row same-bank pattern.
  const int swz = (l15 & 7) << 4;
  int wroff[8];                            // u32 offsets: s = 16nf+4q+{2p,2p+1}
  #pragma unroll
  for (int nf = 0; nf < 4; ++nf)
    #pragma unroll
    for (int p = 0; p < 2; ++p)
      wroff[2 * nf + p] = (l15 * 128 + ((nf * 32 + quad * 8 + p * 4) ^ swz)) >> 2;
  const int rd0 = (l15 * 128 + ((quad * 16) ^ swz)) >> 2;        // s = 8q..8q+7
  const int rd1 = (l15 * 128 + ((64 + quad * 16) ^ swz)) >> 2;   // s = 32+8q..+7
  const size_t QKbase = (size_t)b * Tn * Hn;
  const size_t Vbase  = (size_t)b * Hn * Tn;
  const int tbase = (tile << 6) + (quarter << 4);  // this block's 16 rows
  const int tg = tbase + l15;                      // this lane's query row t

  const size_t qrow = QKbase + (size_t)tg * Hn;
  const bf16x8 qf0 = *(const bf16x8*)(qb + qrow + quad * 8);     // B[n=t][k=h]
  const bf16x8 qf1 = *(const bf16x8*)(qb + qrow + 32 + quad * 8);

  f32x4 acc[4] = {};
  bf16x8 kf[8], vf[8];
  auto loadK = [&](int ch) {               // A[m=s][k=h] frags for S^T
    const int s0 = ch << 6;
    #pragma unroll
    for (int nf = 0; nf < 4; ++nf) {
      const size_t kr = QKbase + (size_t)(s0 + 16 * nf + l15) * Hn;
      kf[2 * nf]     = *(const bf16x8*)(kb + kr + quad * 8);
      kf[2 * nf + 1] = *(const bf16x8*)(kb + kr + 32 + quad * 8);
    }
  };
  auto loadV = [&](int ch) {               // B[n=h][k=s] frags for PV
    const int s0 = ch << 6;
    #pragma unroll
    for (int nf = 0; nf < 4; ++nf) {
      const size_t vr = Vbase + (size_t)(16 * nf + l15) * Tn + s0;
      vf[2 * nf]     = *(const bf16x8*)(vT + vr + quad * 8);
      vf[2 * nf + 1] = *(const bf16x8*)(vT + vr + 32 + quad * 8);
    }
  };

  if (w < nch) { loadK(w); loadV(w); }     // this wave's first owned chunk
  for (int ch = w; ch < nch; ch += 4) {
    const int s0 = ch << 6;
    f32x4 sc[4] = {};                      // D[s][t]: lane&15 = t
    __builtin_amdgcn_s_setprio(1);
    #pragma unroll
    for (int nf = 0; nf < 4; ++nf) {
      sc[nf] = MFMA(kf[2 * nf], qf0, sc[nf]);
      sc[nf] = MFMA(kf[2 * nf + 1], qf1, sc[nf]);
    }
    __builtin_amdgcn_s_setprio(0);
    const int nx = ch + 4;
    if (nx < nch) loadK(nx);               // kf dead: next-K under exp/PV
    const bool diag = (ch == tile);
    #pragma unroll
    for (int nf = 0; nf < 4; ++nf) {
      float4 rl4 = *(const float4*)&rcpl[s0 + 16 * nf + 4 * quad];
      float p[4];
      #pragma unroll
      for (int r = 0; r < 4; ++r) {
        float v = sc[nf][r];
        const int s = s0 + 16 * nf + 4 * quad + r;
        if (diag && tg < s) v = -INFINITY;           // causal: exp2(-inf)=0
        p[r] = fexp2(v) * (&rl4.x)[r];               // P = E/L in [0,1]
      }
      plds[w][wroff[2 * nf]]     = pack2(p[0], p[1]);
      plds[w][wroff[2 * nf + 1]] = pack2(p[2], p[3]);
    }
    const bf16x8 a0 = ldp(&plds[w][rd0]);  // typed u32: order preserved
    const bf16x8 a1 = ldp(&plds[w][rd1]);
    __builtin_amdgcn_s_setprio(1);
    #pragma unroll
    for (int nf = 0; nf < 4; ++nf) {       // D[t][h]: lane&15=h, t=4q+r
      acc[nf] = MFMA(a0, vf[2 * nf], acc[nf]);
      acc[nf] = MFMA(a1, vf[2 * nf + 1], acc[nf]);
    }
    __builtin_amdgcn_s_setprio(0);
    if (nx < nch) loadV(nx);               // vf dead: next-V under next QK
  }

  // cross-wave reduction of the 4 partial accumulators, then one plain store
  #pragma unroll
  for (int nf = 0; nf < 4; ++nf)
    #pragma unroll
    for (int r = 0; r < 4; ++r)
      red[w][quad * 4 + r][16 * nf + l15] = acc[nf][r];
  __syncthreads();
  {
    const int row = tid >> 4, c4 = (tid & 15) * 4;  // 16 rows x 16 col-quads
    float4 s0 = *(const float4*)(&red[0][row][c4]);
    float4 s1 = *(const float4*)(&red[1][row][c4]);
    float4 s2 = *(const float4*)(&red[2][row][c4]);
    float4 s3 = *(const float4*)(&red[3][row][c4]);
    float4 t;
    t.x = (s0.x + s1.x) + (s2.x + s3.x);
    t.y = (s0.y + s1.y) + (s2.y + s3.y);
    t.z = (s0.z + s1.z) + (s2.z + s3.z);
    t.w = (s0.w + s1.w) + (s2.w + s3.w);
    *(float4*)(&out[QKbase + (size_t)(tbase + row) * Hn + c4]) = t;
  }
}

extern "C" void kernel_launch(void* const* d_in, const int* in_sizes, int n_in,
                              void* d_out, int out_size, void* d_ws, size_t ws_size,
                              hipStream_t stream) {
  const float* x  = (const float*)d_in[0];
  const float* Wq = (const float*)d_in[1];
  const float* Wk = (const float*)d_in[2];
  const float* Wv = (const float*)d_in[3];
  char* ws = (char*)d_ws;                          // needs ~6.6 MB
  short* qb   = (short*)(ws);                      // 2 MB (T,H) (q pre-scaled)
  short* kb   = (short*)(ws + 2097152);            // 2 MB (T,H)
  short* vT   = (short*)(ws + 4194304);            // 2 MB (H,T)
  short* WbT  = (short*)(ws + 6291456);            // 144 KB
  float* Lsum = (float*)(ws + 6438912);            // 64 KB dense column sums
  float* outp = (float*)d_out;

  hipLaunchKernelGGL(wconv_kernel, dim3(288), dim3(256), 0, stream, Wq, Wk, Wv, WbT, Lsum);
  hipLaunchKernelGGL(proj_kernel, dim3(Bn * Tn / 16), dim3(256), 0, stream, x, WbT, qb, kb, vT);
  hipLaunchKernelGGL(colstats_kernel, dim3(2048), dim3(256), 0, stream, qb, kb, Lsum);
  hipLaunchKernelGGL(outg_kernel, dim3(1024), dim3(256), 0, stream, qb, kb, vT, Lsum, outp);
}

// Round 13
// 144.340 us; speedup vs baseline: 1.3204x; 1.0461x over previous
//
#include <hip/hip_runtime.h>
#include <hip/hip_bf16.h>
#include <math.h>

#define Bn 8
#define Tn 2048
#define Cn 384
#define Hn 64
#define SCALE2 0.07362241f            // 384^-0.5 * log2(e); pre-folded into Wq

using bf16x8 = __attribute__((ext_vector_type(8))) short;  // 8 bf16 = 4 VGPRs
using f32x4  = __attribute__((ext_vector_type(4))) float;
using u32x4  = __attribute__((ext_vector_type(4))) unsigned;

#define MFMA(a, b, c) __builtin_amdgcn_mfma_f32_16x16x32_bf16((a), (b), (c), 0, 0, 0)

static __device__ __forceinline__ short f2bf(float f) {  // RNE fp32->bf16
  unsigned u = __float_as_uint(f);
  u += 0x7fffu + ((u >> 16) & 1u);
  return (short)(u >> 16);
}
static __device__ __forceinline__ float fexp2(float x) {  // v_exp_f32 (base-2)
#if __has_builtin(__builtin_amdgcn_exp2f)
  return __builtin_amdgcn_exp2f(x);
#else
  return exp2f(x);
#endif
}
static __device__ __forceinline__ float frcp(float x) {   // v_rcp_f32 (~1ulp)
#if __has_builtin(__builtin_amdgcn_rcpf)
  return __builtin_amdgcn_rcpf(x);
#else
  return 1.0f / x;
#endif
}
static __device__ __forceinline__ unsigned pack2(float lo, float hi) {
  return (unsigned)(unsigned short)f2bf(lo) | ((unsigned)(unsigned short)f2bf(hi) << 16);
}
// Typed (TBAA-safe) LDS 16B gather: 4 x u32 loads, compiler merges to b128.
static __device__ __forceinline__ bf16x8 ldp(const unsigned* p) {
  u32x4 t; t[0] = p[0]; t[1] = p[1]; t[2] = p[2]; t[3] = p[3];
  return __builtin_bit_cast(bf16x8, t);
}

// ---------------- K0: W -> WbT (192x384) bf16 (Wq pre-scaled) + zero Lsum ---
__global__ __launch_bounds__(256) void wconv_kernel(
    const float* __restrict__ Wq, const float* __restrict__ Wk,
    const float* __restrict__ Wv, short* __restrict__ WbT,
    float* __restrict__ Lsum) {
  int idx = blockIdx.x * 256 + threadIdx.x;  // n*384 + k, 73728 total
  if (idx < Bn * Tn) Lsum[idx] = 0.f;        // 16384 floats, pre-colstats
  int n = idx / 384, k = idx - n * 384;
  const float* W = (n < 64) ? Wq : (n < 128) ? Wk : Wv;
  float wv = W[k * 64 + (n & 63)];
  if (n < 64) wv *= SCALE2;                  // fold score scale into q
  WbT[idx] = f2bf(wv);
}

// ---------------- K1: proj GEMM, 16-row tiles (1024 blocks, 4/CU) -----------
__global__ __launch_bounds__(256) void proj_kernel(
    const float* __restrict__ x, const short* __restrict__ WbT,
    short* __restrict__ qb, short* __restrict__ kb, short* __restrict__ vT) {
  __shared__ short xs[16][392];    // stride 392: banks 2-way (free)
  __shared__ short vtile[64][20];  // v-tile transpose bounce
  const int tid = threadIdx.x;
  const int t0 = blockIdx.x * 16;  // global row (b*2048 + t)
  const float* xb = x + (size_t)t0 * Cn;
  #pragma unroll
  for (int i = 0; i < 6; ++i) {
    int j = tid + i * 256;  // float4 index, 1536 total
    int row = j / 96, colv = (j - row * 96) * 4;
    float4 v = *(const float4*)(xb + row * Cn + colv);
    short4 s4; s4.x = f2bf(v.x); s4.y = f2bf(v.y); s4.z = f2bf(v.z); s4.w = f2bf(v.w);
    *(short4*)(&xs[row][colv]) = s4;
  }
  __syncthreads();
  const int w = tid >> 6, l15 = tid & 15, quad = (tid & 63) >> 4;
  f32x4 acc[3] = {};
  for (int ks = 0; ks < 12; ++ks) {
    bf16x8 a = *(const bf16x8*)(&xs[l15][ks * 32 + quad * 8]);
    #pragma unroll
    for (int cf = 0; cf < 3; ++cf) {
      bf16x8 bfr = *(const bf16x8*)(WbT + (size_t)(48 * w + 16 * cf + l15) * Cn + ks * 32 + quad * 8);
      acc[cf] = MFMA(a, bfr, acc[cf]);
    }
  }
  #pragma unroll
  for (int cf = 0; cf < 3; ++cf) {
    int cbase = 48 * w + 16 * cf, c = cbase + l15;
    #pragma unroll
    for (int r = 0; r < 4; ++r) {
      int row = t0 + quad * 4 + r;
      short val = f2bf(acc[cf][r]);
      if (cbase < 64)       qb[(size_t)row * Hn + c] = val;
      else if (cbase < 128) kb[(size_t)row * Hn + (c - 64)] = val;
      else                  vtile[c - 128][quad * 4 + r] = val;
    }
  }
  __syncthreads();
  const int b = t0 >> 11, t0l = t0 & 2047;
  int h = tid >> 2, tseg = (tid & 3) * 4;
  *(short4*)(vT + ((size_t)(b * Hn + h)) * Tn + t0l + tseg) =
      *(const short4*)(&vtile[h][tseg]);
}

// ---------------- K2: column exp-sums -> atomicAdd Lsum (high-TLP) ----------
// 2048 blocks x 256 thr. launch_bounds(256,2): the ONLY hint this toolchain's
// allocator tolerates (r12 measured: (256,4) -> VGPR squeezed to 64 + spill;
// (256,2) in r3/r4 -> healthy allocation). Natural VGPR ~90 -> ~5 blocks/CU
// by arithmetic = the TLP that hides the L2 chunk-load latency chain.
// Pair (colchunk j: 32-j t-groups) + (colchunk 31-j: j+1) = 33 items;
// unit = (b = bid&7, j, u sixteenth): 2-3 items each. Fixed s-chunk per run
// -> column sums accumulate in 4 registers (no cross-lane, no LDS atomics).
// q pre-scaled: sc is already the exp2 exponent.
__global__ __launch_bounds__(256, 2) void colstats_kernel(
    const short* __restrict__ qb, const short* __restrict__ kb,
    float* __restrict__ Lsum) {
  const int bid = blockIdx.x;
  const int b = bid & 7;                   // XCD-locked batch
  const int rem = bid >> 3;                // 0..255
  const int j = rem >> 4, u = rem & 15;
  const int lo = (u * 33) >> 4, hi = ((u + 1) * 33) >> 4;  // 2-3 items
  const int big = 32 - j;
  const int tid = threadIdx.x, w = tid >> 6, l15 = tid & 15, quad = (tid & 63) >> 4;
  __shared__ float redl[64][17];

  auto run = [&](const int i, const int k0, const int k1) {
    const int s0 = i << 6;
    float l[4] = {0.f, 0.f, 0.f, 0.f};
    const int n = k1 - k0;
    if (n > 0) {                           // block-uniform: barrier-safe
      bf16x8 bk[8];
      #pragma unroll
      for (int nf = 0; nf < 4; ++nf) {
        const size_t krow = (size_t)(b * Tn + s0 + 16 * nf + l15) * Hn;
        bk[2 * nf]     = *(const bf16x8*)(kb + krow + quad * 8);
        bk[2 * nf + 1] = *(const bf16x8*)(kb + krow + 32 + quad * 8);
      }
      auto cload = [&](bf16x8& A0, bf16x8& A1, int k) {
        size_t ar = (size_t)(b * Tn + ((i + k) << 6) + 16 * w + l15) * Hn;
        A0 = *(const bf16x8*)(qb + ar + quad * 8);
        A1 = *(const bf16x8*)(qb + ar + 32 + quad * 8);
      };
      auto ccomp = [&](bf16x8 A0, bf16x8 A1, int k) {
        f32x4 sc[4] = {};
        __builtin_amdgcn_s_setprio(1);
        #pragma unroll
        for (int nf = 0; nf < 4; ++nf) {
          sc[nf] = MFMA(A0, bk[2 * nf], sc[nf]);
          sc[nf] = MFMA(A1, bk[2 * nf + 1], sc[nf]);
        }
        __builtin_amdgcn_s_setprio(0);
        const bool diag = (k == 0);
        const int tb = ((i + k) << 6) + 16 * w + quad * 4;
        #pragma unroll
        for (int nf = 0; nf < 4; ++nf) {
          int s = s0 + 16 * nf + l15;
          #pragma unroll
          for (int r = 0; r < 4; ++r) {
            float v = sc[nf][r];                     // exp2-domain score
            if (diag && (tb + r) < s) v = -INFINITY; // exp2(-inf) = 0
            l[nf] += fexp2(v);
          }
        }
      };
      bf16x8 a0A, a1A, a0B, a1B;           // 2-deep prefetch (reg-lean)
      cload(a0A, a1A, k0);
      if (n > 1) cload(a0B, a1B, k0 + 1);
      int k = k0;
      while (k + 2 < k1) {
        ccomp(a0A, a1A, k);     cload(a0A, a1A, k + 2);
        ccomp(a0B, a1B, k + 1); if (k + 3 < k1) cload(a0B, a1B, k + 3);
        k += 2;
      }
      if (k < k1)     ccomp(a0A, a1A, k);
      if (k + 1 < k1) ccomp(a0B, a1B, k + 1);
    }
    __syncthreads();  // protect redl reuse across runs (uniform count)
    #pragma unroll
    for (int nf = 0; nf < 4; ++nf) redl[16 * nf + l15][w * 4 + quad] = l[nf];
    __syncthreads();
    if (tid < 64) {
      float ls = 0.f;
      #pragma unroll
      for (int q2 = 0; q2 < 16; ++q2) ls += redl[tid][q2];
      atomicAdd(&Lsum[b * Tn + s0 + tid], ls);  // dense column sums
    }
  };
  run(j, lo, min(hi, big));                       // big member: colchunk j
  run(31 - j, max(lo, big) - big, hi - big);      // small: colchunk 31-j
}

// ---------------- K3: out = (exp(QK^T)/L)_tri . vT^T, 16-row strips ---------
// 1024 blocks x 256 thr. launch_bounds(256,2): cap 256 -> natural VGPR ~115
// -> 4 blocks/CU by arithmetic (r12's (256,4) hint squeezed VGPR to 64 and
// cost +20us; this keeps r12's structure with healthy registers).
// Block = (tile = 31-(bid>>5) heavy-first, b = bid&7 XCD-locked, quarter):
// 16 output rows; waves split chunks stride 4.
// Per chunk: loadV(ch) issued FIRST (latency under QK) -> 8 QK MFMA (kf) ->
// loadK(ch+4) (kf dead) -> exp2*rcpL + pack -> per-wave XOR-swizzled LDS
// transpose (typed u32, no barriers) -> 8 PV MFMA -> loadV(ch+4).
// Cross-wave reduce via red[4][16][64]; one coalesced float4 store/elem.
__global__ __launch_bounds__(256, 2) void outg_kernel(
    const short* __restrict__ qb, const short* __restrict__ kb,
    const short* __restrict__ vT, const float* __restrict__ Lsum,
    float* __restrict__ out) {
  const int bid = blockIdx.x;
  const int tile = 31 - (bid >> 5);        // heavy (many-chunk) tiles first
  const int sub = bid & 31;
  const int b = sub & 7, quarter = sub >> 3;
  const int nch = tile + 1;
  const int tid = threadIdx.x, w = tid >> 6, l15 = tid & 15, quad = (tid & 63) >> 4;
  __shared__ alignas(16) unsigned plds[4][512];  // per-wave 2KB P tile (8KB)
  __shared__ alignas(16) float red[4][16][64];   // cross-wave reduce (16KB)
  __shared__ alignas(16) float rcpl[2048];       // 1/L[s] (8KB)

  const int smax = nch << 6;
  for (int s = tid; s < smax; s += 256)    // coalesced; v_rcp (~1ulp)
    rcpl[s] = frcp(Lsum[b * Tn + s]);
  __syncthreads();

  // XOR swizzle: byte ^= (l15&7)<<4 breaks the 128B-row same-bank pattern.
  const int swz = (l15 & 7) << 4;
  int wroff[8];                            // u32 offsets: s = 16nf+4q+{2p,2p+1}
  #pragma unroll
  for (int nf = 0; nf < 4; ++nf)
    #pragma unroll
    for (int p = 0; p < 2; ++p)
      wroff[2 * nf + p] = (l15 * 128 + ((nf * 32 + quad * 8 + p * 4) ^ swz)) >> 2;
  const int rd0 = (l15 * 128 + ((quad * 16) ^ swz)) >> 2;        // s = 8q..8q+7
  const int rd1 = (l15 * 128 + ((64 + quad * 16) ^ swz)) >> 2;   // s = 32+8q..+7
  const size_t QKbase = (size_t)b * Tn * Hn;
  const size_t Vbase  = (size_t)b * Hn * Tn;
  const int tbase = (tile << 6) + (quarter << 4);  // this block's 16 rows
  const int tg = tbase + l15;                      // this lane's query row t

  const size_t qrow = QKbase + (size_t)tg * Hn;
  const bf16x8 qf0 = *(const bf16x8*)(qb + qrow + quad * 8);     // B[n=t][k=h]
  const bf16x8 qf1 = *(const bf16x8*)(qb + qrow + 32 + quad * 8);

  f32x4 acc[4] = {};
  bf16x8 kf[8], vf[8];
  auto loadK = [&](int ch) {               // A[m=s][k=h] frags for S^T
    const int s0 = ch << 6;
    #pragma unroll
    for (int nf = 0; nf < 4; ++nf) {
      const size_t kr = QKbase + (size_t)(s0 + 16 * nf + l15) * Hn;
      kf[2 * nf]     = *(const bf16x8*)(kb + kr + quad * 8);
      kf[2 * nf + 1] = *(const bf16x8*)(kb + kr + 32 + quad * 8);
    }
  };
  auto loadV = [&](int ch) {               // B[n=h][k=s] frags for PV
    const int s0 = ch << 6;
    #pragma unroll
    for (int nf = 0; nf < 4; ++nf) {
      const size_t vr = Vbase + (size_t)(16 * nf + l15) * Tn + s0;
      vf[2 * nf]     = *(const bf16x8*)(vT + vr + quad * 8);
      vf[2 * nf + 1] = *(const bf16x8*)(vT + vr + 32 + quad * 8);
    }
  };

  if (w < nch) { loadK(w); loadV(w); }     // this wave's first owned chunk
  for (int ch = w; ch < nch; ch += 4) {
    const int s0 = ch << 6;
    f32x4 sc[4] = {};                      // D[s][t]: lane&15 = t
    __builtin_amdgcn_s_setprio(1);
    #pragma unroll
    for (int nf = 0; nf < 4; ++nf) {
      sc[nf] = MFMA(kf[2 * nf], qf0, sc[nf]);
      sc[nf] = MFMA(kf[2 * nf + 1], qf1, sc[nf]);
    }
    __builtin_amdgcn_s_setprio(0);
    const int nx = ch + 4;
    if (nx < nch) loadK(nx);               // kf dead: next-K under exp/PV
    const bool diag = (ch == tile);
    #pragma unroll
    for (int nf = 0; nf < 4; ++nf) {
      float4 rl4 = *(const float4*)&rcpl[s0 + 16 * nf + 4 * quad];
      float p[4];
      #pragma unroll
      for (int r = 0; r < 4; ++r) {
        float v = sc[nf][r];
        const int s = s0 + 16 * nf + 4 * quad + r;
        if (diag && tg < s) v = -INFINITY;           // causal: exp2(-inf)=0
        p[r] = fexp2(v) * (&rl4.x)[r];               // P = E/L in [0,1]
      }
      plds[w][wroff[2 * nf]]     = pack2(p[0], p[1]);
      plds[w][wroff[2 * nf + 1]] = pack2(p[2], p[3]);
    }
    const bf16x8 a0 = ldp(&plds[w][rd0]);  // typed u32: order preserved
    const bf16x8 a1 = ldp(&plds[w][rd1]);
    __builtin_amdgcn_s_setprio(1);
    #pragma unroll
    for (int nf = 0; nf < 4; ++nf) {       // D[t][h]: lane&15=h, t=4q+r
      acc[nf] = MFMA(a0, vf[2 * nf], acc[nf]);
      acc[nf] = MFMA(a1, vf[2 * nf + 1], acc[nf]);
    }
    __builtin_amdgcn_s_setprio(0);
    if (nx < nch) loadV(nx);               // vf dead: next-V under next QK
  }

  // cross-wave reduction of the 4 partial accumulators, then one plain store
  #pragma unroll
  for (int nf = 0; nf < 4; ++nf)
    #pragma unroll
    for (int r = 0; r < 4; ++r)
      red[w][quad * 4 + r][16 * nf + l15] = acc[nf][r];
  __syncthreads();
  {
    const int row = tid >> 4, c4 = (tid & 15) * 4;  // 16 rows x 16 col-quads
    float4 s0 = *(const float4*)(&red[0][row][c4]);
    float4 s1 = *(const float4*)(&red[1][row][c4]);
    float4 s2 = *(const float4*)(&red[2][row][c4]);
    float4 s3 = *(const float4*)(&red[3][row][c4]);
    float4 t;
    t.x = (s0.x + s1.x) + (s2.x + s3.x);
    t.y = (s0.y + s1.y) + (s2.y + s3.y);
    t.z = (s0.z + s1.z) + (s2.z + s3.z);
    t.w = (s0.w + s1.w) + (s2.w + s3.w);
    *(float4*)(&out[QKbase + (size_t)(tbase + row) * Hn + c4]) = t;
  }
}

extern "C" void kernel_launch(void* const* d_in, const int* in_sizes, int n_in,
                              void* d_out, int out_size, void* d_ws, size_t ws_size,
                              hipStream_t stream) {
  const float* x  = (const float*)d_in[0];
  const float* Wq = (const float*)d_in[1];
  const float* Wk = (const float*)d_in[2];
  const float* Wv = (const float*)d_in[3];
  char* ws = (char*)d_ws;                          // needs ~6.6 MB
  short* qb   = (short*)(ws);                      // 2 MB (T,H) (q pre-scaled)
  short* kb   = (short*)(ws + 2097152);            // 2 MB (T,H)
  short* vT   = (short*)(ws + 4194304);            // 2 MB (H,T)
  short* WbT  = (short*)(ws + 6291456);            // 144 KB
  float* Lsum = (float*)(ws + 6438912);            // 64 KB dense column sums
  float* outp = (float*)d_out;

  hipLaunchKernelGGL(wconv_kernel, dim3(288), dim3(256), 0, stream, Wq, Wk, Wv, WbT, Lsum);
  hipLaunchKernelGGL(proj_kernel, dim3(Bn * Tn / 16), dim3(256), 0, stream, x, WbT, qb, kb, vT);
  hipLaunchKernelGGL(colstats_kernel, dim3(2048), dim3(256), 0, stream, qb, kb, Lsum);
  hipLaunchKernelGGL(outg_kernel, dim3(1024), dim3(256), 0, stream, qb, kb, vT, Lsum, outp);
}

// Round 14
// 135.267 us; speedup vs baseline: 1.4089x; 1.0671x over previous
//
#include <hip/hip_runtime.h>
#include <hip/hip_bf16.h>
#include <math.h>

#define Bn 8
#define Tn 2048
#define Cn 384
#define Hn 64
#define SCALE2 0.07362241f            // 384^-0.5 * log2(e); pre-folded into Wq

using bf16x8 = __attribute__((ext_vector_type(8))) short;  // 8 bf16 = 4 VGPRs
using f32x4  = __attribute__((ext_vector_type(4))) float;
using u32x4  = __attribute__((ext_vector_type(4))) unsigned;

#define MFMA(a, b, c) __builtin_amdgcn_mfma_f32_16x16x32_bf16((a), (b), (c), 0, 0, 0)

static __device__ __forceinline__ short f2bf(float f) {  // RNE fp32->bf16
  unsigned u = __float_as_uint(f);
  u += 0x7fffu + ((u >> 16) & 1u);
  return (short)(u >> 16);
}
static __device__ __forceinline__ float fexp2(float x) {  // v_exp_f32 (base-2)
#if __has_builtin(__builtin_amdgcn_exp2f)
  return __builtin_amdgcn_exp2f(x);
#else
  return exp2f(x);
#endif
}
static __device__ __forceinline__ float frcp(float x) {   // v_rcp_f32 (~1ulp)
#if __has_builtin(__builtin_amdgcn_rcpf)
  return __builtin_amdgcn_rcpf(x);
#else
  return 1.0f / x;
#endif
}
static __device__ __forceinline__ unsigned pack2(float lo, float hi) {
  return (unsigned)(unsigned short)f2bf(lo) | ((unsigned)(unsigned short)f2bf(hi) << 16);
}
// Typed (TBAA-safe) LDS 16B gather: 4 x u32 loads, compiler merges to b128.
static __device__ __forceinline__ bf16x8 ldp(const unsigned* p) {
  u32x4 t; t[0] = p[0]; t[1] = p[1]; t[2] = p[2]; t[3] = p[3];
  return __builtin_bit_cast(bf16x8, t);
}

// ---------------- K0: W -> WbT (192x384) bf16 (Wq pre-scaled) + zero Lsum ---
__global__ __launch_bounds__(256) void wconv_kernel(
    const float* __restrict__ Wq, const float* __restrict__ Wk,
    const float* __restrict__ Wv, short* __restrict__ WbT,
    float* __restrict__ Lsum) {
  int idx = blockIdx.x * 256 + threadIdx.x;  // n*384 + k, 73728 total
  if (idx < Bn * Tn) Lsum[idx] = 0.f;        // 16384 floats, pre-colstats
  int n = idx / 384, k = idx - n * 384;
  const float* W = (n < 64) ? Wq : (n < 128) ? Wk : Wv;
  float wv = W[k * 64 + (n & 63)];
  if (n < 64) wv *= SCALE2;                  // fold score scale into q
  WbT[idx] = f2bf(wv);
}

// ---------------- K1: proj GEMM, 16-row tiles (1024 blocks, 4/CU) -----------
__global__ __launch_bounds__(256) void proj_kernel(
    const float* __restrict__ x, const short* __restrict__ WbT,
    short* __restrict__ qb, short* __restrict__ kb, short* __restrict__ vT) {
  __shared__ short xs[16][392];    // stride 392: banks 2-way (free)
  __shared__ short vtile[64][20];  // v-tile transpose bounce
  const int tid = threadIdx.x;
  const int t0 = blockIdx.x * 16;  // global row (b*2048 + t)
  const float* xb = x + (size_t)t0 * Cn;
  #pragma unroll
  for (int i = 0; i < 6; ++i) {
    int j = tid + i * 256;  // float4 index, 1536 total
    int row = j / 96, colv = (j - row * 96) * 4;
    float4 v = *(const float4*)(xb + row * Cn + colv);
    short4 s4; s4.x = f2bf(v.x); s4.y = f2bf(v.y); s4.z = f2bf(v.z); s4.w = f2bf(v.w);
    *(short4*)(&xs[row][colv]) = s4;
  }
  __syncthreads();
  const int w = tid >> 6, l15 = tid & 15, quad = (tid & 63) >> 4;
  f32x4 acc[3] = {};
  for (int ks = 0; ks < 12; ++ks) {
    bf16x8 a = *(const bf16x8*)(&xs[l15][ks * 32 + quad * 8]);
    #pragma unroll
    for (int cf = 0; cf < 3; ++cf) {
      bf16x8 bfr = *(const bf16x8*)(WbT + (size_t)(48 * w + 16 * cf + l15) * Cn + ks * 32 + quad * 8);
      acc[cf] = MFMA(a, bfr, acc[cf]);
    }
  }
  #pragma unroll
  for (int cf = 0; cf < 3; ++cf) {
    int cbase = 48 * w + 16 * cf, c = cbase + l15;
    #pragma unroll
    for (int r = 0; r < 4; ++r) {
      int row = t0 + quad * 4 + r;
      short val = f2bf(acc[cf][r]);
      if (cbase < 64)       qb[(size_t)row * Hn + c] = val;
      else if (cbase < 128) kb[(size_t)row * Hn + (c - 64)] = val;
      else                  vtile[c - 128][quad * 4 + r] = val;
    }
  }
  __syncthreads();
  const int b = t0 >> 11, t0l = t0 & 2047;
  int h = tid >> 2, tseg = (tid & 3) * 4;
  *(short4*)(vT + ((size_t)(b * Hn + h)) * Tn + t0l + tseg) =
      *(const short4*)(&vtile[h][tseg]);
}

// ---------------- K2: column exp-sums -> atomicAdd Lsum (high-TLP) ----------
// 2048 blocks x 256 thr, launch_bounds(256,2) — the only allocator-safe hint
// (r12: (256,4) squeezed VGPR to 64 and regressed; r13: (256,2) healthy).
// Pair (colchunk j: 32-j t-groups) + (colchunk 31-j: j+1) = 33 items;
// unit = (b = bid&7, j, u sixteenth): 2-3 items each. Fixed s-chunk per run
// -> column sums accumulate in 4 registers (no cross-lane, no LDS atomics).
// q pre-scaled: sc is already the exp2 exponent.
__global__ __launch_bounds__(256, 2) void colstats_kernel(
    const short* __restrict__ qb, const short* __restrict__ kb,
    float* __restrict__ Lsum) {
  const int bid = blockIdx.x;
  const int b = bid & 7;                   // XCD-locked batch
  const int rem = bid >> 3;                // 0..255
  const int j = rem >> 4, u = rem & 15;
  const int lo = (u * 33) >> 4, hi = ((u + 1) * 33) >> 4;  // 2-3 items
  const int big = 32 - j;
  const int tid = threadIdx.x, w = tid >> 6, l15 = tid & 15, quad = (tid & 63) >> 4;
  __shared__ float redl[64][17];

  auto run = [&](const int i, const int k0, const int k1) {
    const int s0 = i << 6;
    float l[4] = {0.f, 0.f, 0.f, 0.f};
    const int n = k1 - k0;
    if (n > 0) {                           // block-uniform: barrier-safe
      bf16x8 bk[8];
      #pragma unroll
      for (int nf = 0; nf < 4; ++nf) {
        const size_t krow = (size_t)(b * Tn + s0 + 16 * nf + l15) * Hn;
        bk[2 * nf]     = *(const bf16x8*)(kb + krow + quad * 8);
        bk[2 * nf + 1] = *(const bf16x8*)(kb + krow + 32 + quad * 8);
      }
      auto cload = [&](bf16x8& A0, bf16x8& A1, int k) {
        size_t ar = (size_t)(b * Tn + ((i + k) << 6) + 16 * w + l15) * Hn;
        A0 = *(const bf16x8*)(qb + ar + quad * 8);
        A1 = *(const bf16x8*)(qb + ar + 32 + quad * 8);
      };
      auto ccomp = [&](bf16x8 A0, bf16x8 A1, int k) {
        f32x4 sc[4] = {};
        __builtin_amdgcn_s_setprio(1);
        #pragma unroll
        for (int nf = 0; nf < 4; ++nf) {
          sc[nf] = MFMA(A0, bk[2 * nf], sc[nf]);
          sc[nf] = MFMA(A1, bk[2 * nf + 1], sc[nf]);
        }
        __builtin_amdgcn_s_setprio(0);
        const bool diag = (k == 0);
        const int tb = ((i + k) << 6) + 16 * w + quad * 4;
        #pragma unroll
        for (int nf = 0; nf < 4; ++nf) {
          int s = s0 + 16 * nf + l15;
          #pragma unroll
          for (int r = 0; r < 4; ++r) {
            float v = sc[nf][r];                     // exp2-domain score
            if (diag && (tb + r) < s) v = -INFINITY; // exp2(-inf) = 0
            l[nf] += fexp2(v);
          }
        }
      };
      bf16x8 a0A, a1A, a0B, a1B;           // 2-deep prefetch (reg-lean)
      cload(a0A, a1A, k0);
      if (n > 1) cload(a0B, a1B, k0 + 1);
      int k = k0;
      while (k + 2 < k1) {
        ccomp(a0A, a1A, k);     cload(a0A, a1A, k + 2);
        ccomp(a0B, a1B, k + 1); if (k + 3 < k1) cload(a0B, a1B, k + 3);
        k += 2;
      }
      if (k < k1)     ccomp(a0A, a1A, k);
      if (k + 1 < k1) ccomp(a0B, a1B, k + 1);
    }
    __syncthreads();  // protect redl reuse across runs (uniform count)
    #pragma unroll
    for (int nf = 0; nf < 4; ++nf) redl[16 * nf + l15][w * 4 + quad] = l[nf];
    __syncthreads();
    if (tid < 64) {
      float ls = 0.f;
      #pragma unroll
      for (int q2 = 0; q2 < 16; ++q2) ls += redl[tid][q2];
      atomicAdd(&Lsum[b * Tn + s0 + tid], ls);  // dense column sums
    }
  };
  run(j, lo, min(hi, big));                       // big member: colchunk j
  run(31 - j, max(lo, big) - big, hi - big);      // small: colchunk 31-j
}

// ---------------- K3: out = (exp(QK^T)/L)_tri . vT^T — r4's 32-row kernel ---
// 512 blocks x 256 thr, 2/CU, launch_bounds(256,2) (allocator-safe).
// Block = (b = bid&7 XCD-locked, tile heavy-first, half): 32 output rows.
// Each wave reuses its kf/vf for BOTH 16-row strips (halves K/V L2 traffic —
// the r3 lesson that r9-r13's 16-row strips undid, costing ~12us).
// kf double-buffered (ping-pong A/B, loads issue right after QK MFMAs),
// vf single-buffered tail-issued. rcpL precomputed to LDS; P'=E/L in [0,1].
// Per-wave XOR-swizzled LDS transpose (typed u32, no barriers).
__global__ __launch_bounds__(256, 2) void outg_kernel(
    const short* __restrict__ qb, const short* __restrict__ kb,
    const short* __restrict__ vT, const float* __restrict__ Lsum,
    float* __restrict__ out) {
  const int bid = blockIdx.x;
  const int b = bid & 7;                   // XCD-locked batch
  const int rest = bid >> 3;               // 0..63
  const int tile = 31 - (rest >> 1);       // heavy (many-chunk) tiles first
  const int half = rest & 1;
  const int nch = tile + 1;
  const int tid = threadIdx.x, w = tid >> 6, l15 = tid & 15, quad = (tid & 63) >> 4;
  __shared__ alignas(16) unsigned plds[4][512];  // per-wave 2KB P tile (8KB)
  __shared__ alignas(16) float red[4][32][64];   // cross-wave reduce (32KB)
  __shared__ alignas(16) float rcpl[2048];       // 1/L[s] (8KB)

  const int smax = nch << 6;
  for (int s = tid; s < smax; s += 256)    // coalesced; v_rcp (~1ulp)
    rcpl[s] = frcp(Lsum[b * Tn + s]);
  __syncthreads();

  // XOR swizzle: byte ^= (l15&7)<<4 breaks the 128B-row same-bank pattern.
  const int swz = (l15 & 7) << 4;
  int wroff[8];                            // u32 offsets: s = 16nf+4q+{2p,2p+1}
  #pragma unroll
  for (int nf = 0; nf < 4; ++nf)
    #pragma unroll
    for (int p = 0; p < 2; ++p)
      wroff[2 * nf + p] = (l15 * 128 + ((nf * 32 + quad * 8 + p * 4) ^ swz)) >> 2;
  const int rd0 = (l15 * 128 + ((quad * 16) ^ swz)) >> 2;        // s = 8q..8q+7
  const int rd1 = (l15 * 128 + ((64 + quad * 16) ^ swz)) >> 2;   // s = 32+8q..+7
  const size_t QKbase = (size_t)b * Tn * Hn;
  const size_t Vbase  = (size_t)b * Hn * Tn;
  const int tbase = (tile << 6) + (half << 5);  // this block's 32 output rows
  const int tg0 = tbase + l15;                  // strip0 lane query row
  const int tg1 = tbase + 16 + l15;             // strip1 lane query row

  const size_t qrow0 = QKbase + (size_t)(tbase + l15) * Hn;
  const size_t qrow1 = qrow0 + 16 * Hn;
  const bf16x8 qf00 = *(const bf16x8*)(qb + qrow0 + quad * 8);   // B[n=t][k=h]
  const bf16x8 qf01 = *(const bf16x8*)(qb + qrow0 + 32 + quad * 8);
  const bf16x8 qf10 = *(const bf16x8*)(qb + qrow1 + quad * 8);
  const bf16x8 qf11 = *(const bf16x8*)(qb + qrow1 + 32 + quad * 8);

  f32x4 acc0[4] = {}, acc1[4] = {};
  bf16x8 kfA[8], kfB[8], vf[8];
  auto loadK = [&](bf16x8 (&kf)[8], int ch) {  // A[m=s][k=h] frags for S^T
    const int s0 = ch << 6;
    #pragma unroll
    for (int nf = 0; nf < 4; ++nf) {
      const size_t kr = QKbase + (size_t)(s0 + 16 * nf + l15) * Hn;
      kf[2 * nf]     = *(const bf16x8*)(kb + kr + quad * 8);
      kf[2 * nf + 1] = *(const bf16x8*)(kb + kr + 32 + quad * 8);
    }
  };
  auto loadV = [&](int ch) {               // B[n=h][k=s] frags for PV (raw vT)
    const int s0 = ch << 6;
    #pragma unroll
    for (int nf = 0; nf < 4; ++nf) {
      const size_t vr = Vbase + (size_t)(16 * nf + l15) * Tn + s0;
      vf[2 * nf]     = *(const bf16x8*)(vT + vr + quad * 8);
      vf[2 * nf + 1] = *(const bf16x8*)(vT + vr + 32 + quad * 8);
    }
  };
  // strip = {exp*rcpL + pack -> LDS -> read back A-frags -> 8 PV MFMA into acc}
  auto strip = [&](const f32x4 (&sc)[4], const float (&rl)[16], int s0,
                   bool diag, int tg, f32x4 (&acc)[4]) {
    #pragma unroll
    for (int nf = 0; nf < 4; ++nf) {
      float ev[4];
      #pragma unroll
      for (int r = 0; r < 4; ++r) {
        float v = sc[nf][r];               // q pre-scaled: exp2 exponent
        const int s = s0 + 16 * nf + quad * 4 + r;
        if (diag && tg < s) v = -INFINITY;           // causal: exp2(-inf)=0
        ev[r] = fexp2(v) * rl[nf * 4 + r];           // P' = E/L in [0,1]
      }
      plds[w][wroff[2 * nf]]     = pack2(ev[0], ev[1]);
      plds[w][wroff[2 * nf + 1]] = pack2(ev[2], ev[3]);
    }
    // typed u32 reads: may-alias with the stores above -> order preserved;
    // DS pipe in-order per wave -> data correct, no vmcnt drain.
    const bf16x8 a0 = ldp(&plds[w][rd0]);
    const bf16x8 a1 = ldp(&plds[w][rd1]);
    __builtin_amdgcn_s_setprio(1);
    #pragma unroll
    for (int nf = 0; nf < 4; ++nf) {       // D[t][h]: lane&15 = h, t = 4q+r
      acc[nf] = MFMA(a0, vf[2 * nf], acc[nf]);
      acc[nf] = MFMA(a1, vf[2 * nf + 1], acc[nf]);
    }
    __builtin_amdgcn_s_setprio(0);
  };
  auto body = [&](int ch, const bf16x8 (&CUR)[8], bf16x8 (&NXT)[8]) {
    const int s0 = ch << 6;
    const int nx = ch + 4;
    f32x4 sc0[4] = {}, sc1[4] = {};        // D[s][t]: lane&15 = t
    __builtin_amdgcn_s_setprio(1);
    #pragma unroll
    for (int nf = 0; nf < 4; ++nf) {
      sc0[nf] = MFMA(CUR[2 * nf], qf00, sc0[nf]);
      sc0[nf] = MFMA(CUR[2 * nf + 1], qf01, sc0[nf]);
    }
    #pragma unroll
    for (int nf = 0; nf < 4; ++nf) {
      sc1[nf] = MFMA(CUR[2 * nf], qf10, sc1[nf]);
      sc1[nf] = MFMA(CUR[2 * nf + 1], qf11, sc1[nf]);
    }
    __builtin_amdgcn_s_setprio(0);
    if (nx < nch) loadK(NXT, nx);          // early issue, lands in other buffer
    float rl[16];                          // rcpL regs, shared by both strips
    #pragma unroll
    for (int nf = 0; nf < 4; ++nf)
      #pragma unroll
      for (int r = 0; r < 4; ++r)
        rl[nf * 4 + r] = rcpl[s0 + 16 * nf + quad * 4 + r];
    const bool diag = (ch == tile);
    strip(sc0, rl, s0, diag, tg0, acc0);   // strip0: exp->LDS->PV
    strip(sc1, rl, s0, diag, tg1, acc1);   // strip1 reuses same LDS region
    if (nx < nch) loadV(nx);               // tail issue (vf consumed above)
  };

  if (w < nch) { loadK(kfA, w); loadV(w); }    // this wave's first owned chunk
  for (int ch = w; ch < nch; ch += 8) {    // explicit A/B ping-pong (static)
    body(ch, kfA, kfB);
    if (ch + 4 < nch) body(ch + 4, kfB, kfA);
  }

  // cross-wave reduction of the 4 partial accumulators, then one plain store
  #pragma unroll
  for (int nf = 0; nf < 4; ++nf)
    #pragma unroll
    for (int r = 0; r < 4; ++r) {
      red[w][quad * 4 + r][16 * nf + l15]      = acc0[nf][r];
      red[w][16 + quad * 4 + r][16 * nf + l15] = acc1[nf][r];
    }
  __syncthreads();
  {
    const int row = tid >> 3, c8 = (tid & 7) * 8;   // 32 rows x 8 lanes x 8 cols
    float4 t0 = {0.f, 0.f, 0.f, 0.f}, t1 = {0.f, 0.f, 0.f, 0.f};
    #pragma unroll
    for (int ww = 0; ww < 4; ++ww) {
      float4 s0 = *(const float4*)(&red[ww][row][c8]);
      float4 s1 = *(const float4*)(&red[ww][row][c8 + 4]);
      t0.x += s0.x; t0.y += s0.y; t0.z += s0.z; t0.w += s0.w;
      t1.x += s1.x; t1.y += s1.y; t1.z += s1.z; t1.w += s1.w;
    }
    float* o = &out[QKbase + (size_t)(tbase + row) * Hn + c8];
    *(float4*)(o) = t0;
    *(float4*)(o + 4) = t1;
  }
}

extern "C" void kernel_launch(void* const* d_in, const int* in_sizes, int n_in,
                              void* d_out, int out_size, void* d_ws, size_t ws_size,
                              hipStream_t stream) {
  const float* x  = (const float*)d_in[0];
  const float* Wq = (const float*)d_in[1];
  const float* Wk = (const float*)d_in[2];
  const float* Wv = (const float*)d_in[3];
  char* ws = (char*)d_ws;                          // needs ~6.6 MB
  short* qb   = (short*)(ws);                      // 2 MB (T,H) (q pre-scaled)
  short* kb   = (short*)(ws + 2097152);            // 2 MB (T,H)
  short* vT   = (short*)(ws + 4194304);            // 2 MB (H,T)
  short* WbT  = (short*)(ws + 6291456);            // 144 KB
  float* Lsum = (float*)(ws + 6438912);            // 64 KB dense column sums
  float* outp = (float*)d_out;

  hipLaunchKernelGGL(wconv_kernel, dim3(288), dim3(256), 0, stream, Wq, Wk, Wv, WbT, Lsum);
  hipLaunchKernelGGL(proj_kernel, dim3(Bn * Tn / 16), dim3(256), 0, stream, x, WbT, qb, kb, vT);
  hipLaunchKernelGGL(colstats_kernel, dim3(2048), dim3(256), 0, stream, qb, kb, Lsum);
  hipLaunchKernelGGL(outg_kernel, dim3(512), dim3(256), 0, stream, qb, kb, vT, Lsum, outp);
}